// Round 1
// baseline (5458.921 us; speedup 1.0000x reference)
//
#include <hip/hip_runtime.h>
#include <cstdint>
#include <cstddef>

#define B_    256
#define W_    41
#define D_    512
#define K_    4096
#define L_    8
#define NROWS (B_ * W_)            // 10496
#define QOUT_ELEMS (NROWS * D_)    // 5373952
#define IDX_ELEMS  (NROWS * L_)    // 83968

#define BM 128
#define BN 128
#define BKD 8
#define TM 8
#define TN 8

// -------- init: residual = x, rowNorm[n] = (float)sum(x^2) --------
__global__ __launch_bounds__(256)
void rq_init(const float* __restrict__ x, float* __restrict__ R,
             float* __restrict__ rowNorm)
{
    const int wave = threadIdx.x >> 6;
    const int lane = threadIdx.x & 63;
    const int n = blockIdx.x * 4 + wave;
    const float4* xp = (const float4*)(x + (size_t)n * D_);
    float4* rp = (float4*)(R + (size_t)n * D_);
    double asum = 0.0;
#pragma unroll
    for (int u = 0; u < 2; ++u) {
        const int idx = u * 64 + lane;
        float4 v = xp[idx];
        rp[idx] = v;
        asum += (double)v.x * v.x + (double)v.y * v.y
              + (double)v.z * v.z + (double)v.w * v.w;
    }
#pragma unroll
    for (int off = 32; off > 0; off >>= 1)
        asum += __shfl_down(asum, off, 64);
    if (lane == 0) rowNorm[n] = (float)asum;
}

// -------- distance GEMM + argmin --------
// M[n][k] = ascending-d fp32 FMA chain (bit-matches BLAS sgemm per element).
// comparator c = fl(rowNorm - 2*M)  (2*M exact; fused or not, identical).
// key = (bits(c)<<32)|k, u64 min == lexicographic (c, k) min == np.argmin tie rule.
__global__ __launch_bounds__(256)
void rq_dist_argmin(const float* __restrict__ R, const float* __restrict__ E,
                    const float* __restrict__ rowNorm,
                    unsigned long long* __restrict__ keys)
{
    __shared__ float As[BKD][BM];
    __shared__ float Bs[BKD][BN];
    __shared__ unsigned long long red[BM][17];

    const int t  = threadIdx.x;
    const int tx = t & 15;
    const int ty = t >> 4;
    const int rowBase = blockIdx.x * BM;
    const int colBase = blockIdx.y * BN;

    const int lm   = t >> 1;         // 0..127: tile row loaded by this thread
    const int lseg = (t & 1) * 4;    // 0 or 4: d-offset within 8-wide slab

    const float* Aptr = R + (size_t)(rowBase + lm) * D_ + lseg;
    const float* Bptr = E + (size_t)(colBase + lm) * D_ + lseg;

    float acc[TM][TN];
#pragma unroll
    for (int i = 0; i < TM; ++i)
#pragma unroll
        for (int j = 0; j < TN; ++j) acc[i][j] = 0.0f;

    for (int dt = 0; dt < D_; dt += BKD) {
        const float4 av = *(const float4*)(Aptr + dt);
        const float4 bv = *(const float4*)(Bptr + dt);
        __syncthreads();
        As[lseg + 0][lm] = av.x; As[lseg + 1][lm] = av.y;
        As[lseg + 2][lm] = av.z; As[lseg + 3][lm] = av.w;
        Bs[lseg + 0][lm] = bv.x; Bs[lseg + 1][lm] = bv.y;
        Bs[lseg + 2][lm] = bv.z; Bs[lseg + 3][lm] = bv.w;
        __syncthreads();
#pragma unroll
        for (int dd = 0; dd < BKD; ++dd) {   // ascending d: exact chain order
            float a0[TM], b0[TN];
            *(float4*)&a0[0] = *(const float4*)&As[dd][ty * TM];
            *(float4*)&a0[4] = *(const float4*)&As[dd][ty * TM + 4];
            *(float4*)&b0[0] = *(const float4*)&Bs[dd][tx * TN];
            *(float4*)&b0[4] = *(const float4*)&Bs[dd][tx * TN + 4];
#pragma unroll
            for (int i = 0; i < TM; ++i)
#pragma unroll
                for (int j = 0; j < TN; ++j)
                    acc[i][j] = fmaf(a0[i], b0[j], acc[i][j]);
        }
    }

#pragma unroll
    for (int i = 0; i < TM; ++i) {
        const int row = rowBase + ty * TM + i;
        const float An = rowNorm[row];
        unsigned long long best = 0xFFFFFFFFFFFFFFFFull;
#pragma unroll
        for (int j = 0; j < TN; ++j) {
            const float c = __fsub_rn(An, 2.0f * acc[i][j]);  // c > 0 always
            const unsigned long long key =
                ((unsigned long long)__float_as_uint(c) << 32)
                | (unsigned int)(colBase + tx * TN + j);
            if (key < best) best = key;
        }
        red[ty * TM + i][tx] = best;
    }
    __syncthreads();
    if (t < BM) {
        unsigned long long b = red[t][0];
#pragma unroll
        for (int j = 1; j < 16; ++j)
            if (red[t][j] < b) b = red[t][j];
        atomicMin(&keys[rowBase + t], b);
    }
}

// -------- per-layer update: STE epilogue, exact fp32 replication --------
__global__ __launch_bounds__(256)
void rq_update(float* __restrict__ R, const float* __restrict__ E,
               const unsigned long long* __restrict__ keys,
               float* __restrict__ qout, float* __restrict__ idxOut,
               float* __restrict__ rowNorm, double* __restrict__ lossAcc,
               int layer)
{
    const int wave = threadIdx.x >> 6;
    const int lane = threadIdx.x & 63;
    const int n = blockIdx.x * 4 + wave;
    const unsigned long long key = keys[n];
    const int k = (int)(key & 0xFFFFFFFFull);

    const float4* ep = (const float4*)(E + (size_t)k * D_);
    float4* rp = (float4*)(R + (size_t)n * D_);
    float4* qp = (float4*)(qout + (size_t)n * D_);

    double lsum = 0.0, asum = 0.0;
#pragma unroll
    for (int u = 0; u < 2; ++u) {
        const int idx = u * 64 + lane;
        float4 r4 = rp[idx];
        float4 q4 = ep[idx];
        float4 o4 = qp[idx];
        float rnew[4], qo[4];
        float rr[4] = {r4.x, r4.y, r4.z, r4.w};
        float qq[4] = {q4.x, q4.y, q4.z, q4.w};
        float oo[4] = {o4.x, o4.y, o4.z, o4.w};
#pragma unroll
        for (int c = 0; c < 4; ++c) {
            const float d1  = __fsub_rn(qq[c], rr[c]);   // quantized - residual
            const float qst = __fadd_rn(rr[c], d1);      // straight-through value
            rnew[c] = __fsub_rn(rr[c], qst);
            qo[c]   = __fadd_rn(oo[c], qst);
            lsum += (double)d1 * (double)d1;
            asum += (double)rnew[c] * (double)rnew[c];
        }
        rp[idx] = make_float4(rnew[0], rnew[1], rnew[2], rnew[3]);
        qp[idx] = make_float4(qo[0], qo[1], qo[2], qo[3]);
    }
#pragma unroll
    for (int off = 32; off > 0; off >>= 1) {
        lsum += __shfl_down(lsum, off, 64);
        asum += __shfl_down(asum, off, 64);
    }
    if (lane == 0) {
        rowNorm[n] = (float)asum;
        atomicAdd(lossAcc, lsum);
        idxOut[(size_t)n * L_ + layer] = (float)k;
    }
}

__global__ void rq_finalize(float* __restrict__ lossOut,
                            const double* __restrict__ lossAcc)
{
    *lossOut = (float)(0.25 * (*lossAcc) / (double)QOUT_ELEMS);
}

extern "C" void kernel_launch(void* const* d_in, const int* in_sizes, int n_in,
                              void* d_out, int out_size, void* d_ws, size_t ws_size,
                              hipStream_t stream)
{
    const float* x  = (const float*)d_in[0];
    const float* cb = (const float*)d_in[1];
    float* out = (float*)d_out;
    char* ws = (char*)d_ws;

    float* R = (float*)ws;                                     // 21,495,808 B
    float* rowNorm = (float*)(ws + 21495808);                  //     41,984 B
    unsigned long long* keys = (unsigned long long*)(ws + 21537792); // 83,968 B
    double* lossAcc = (double*)(ws + 21621760);                //          8 B

    float* idxOut = out + QOUT_ELEMS + 1;

    hipMemsetAsync(d_out, 0, (size_t)out_size * sizeof(float), stream);
    hipMemsetAsync(lossAcc, 0, sizeof(double), stream);

    rq_init<<<NROWS / 4, 256, 0, stream>>>(x, R, rowNorm);

    for (int l = 0; l < L_; ++l) {
        hipMemsetAsync(keys, 0xFF, (size_t)NROWS * sizeof(unsigned long long), stream);
        const float* E = cb + (size_t)l * K_ * D_;
        dim3 grid(NROWS / BM, K_ / BN);
        rq_dist_argmin<<<grid, 256, 0, stream>>>(R, E, rowNorm, keys);
        rq_update<<<NROWS / 4, 256, 0, stream>>>(R, E, keys, out, idxOut,
                                                 rowNorm, lossAcc, l);
    }
    rq_finalize<<<1, 1, 0, stream>>>(out + QOUT_ELEMS, lossAcc);
}